// Round 1
// baseline (549.590 us; speedup 1.0000x reference)
//
#include <hip/hip_runtime.h>
#include <hip/hip_bf16.h>
#include <stdint.h>

#define DIM    1024
#define HEADS  16
#define DHEAD  64
#define SEQ    2048
#define BATCH  4

typedef unsigned short u16;
typedef __attribute__((ext_vector_type(4))) float f32x4;
typedef __attribute__((ext_vector_type(8))) short bf16x8;
typedef __attribute__((ext_vector_type(8))) u16   u16x8;

// 0.125 (1/sqrt(64)) * log2(e): scores computed in log2 domain -> v_exp_f32 is 2^x
#define QSCALE 0.18033688011112042f

__device__ inline u16 f2bf(float f) {
  __hip_bfloat16 h = __float2bfloat16(f);
  return *reinterpret_cast<u16*>(&h);
}

__device__ inline void async_load16(const void* g, void* l) {
  __builtin_amdgcn_global_load_lds((const __attribute__((address_space(1))) void*)g,
                                   (__attribute__((address_space(3))) void*)l, 16, 0, 0);
}

// ---------------- Kernel 1: LayerNorm -> bf16 ----------------
__global__ __launch_bounds__(256) void ln_kernel(const float* __restrict__ x,
                                                 const float* __restrict__ w,
                                                 const float* __restrict__ b,
                                                 u16* __restrict__ h) {
  int row = blockIdx.x;
  int t = threadIdx.x;
  const float4* xr = (const float4*)(x + (size_t)row * DIM);
  float4 v = xr[t];
  float s  = v.x + v.y + v.z + v.w;
  float s2 = v.x*v.x + v.y*v.y + v.z*v.z + v.w*v.w;
  for (int m = 1; m < 64; m <<= 1) { s += __shfl_xor(s, m); s2 += __shfl_xor(s2, m); }
  __shared__ float ss[4], ss2[4];
  int wid = t >> 6;
  if ((t & 63) == 0) { ss[wid] = s; ss2[wid] = s2; }
  __syncthreads();
  s  = ss[0] + ss[1] + ss[2] + ss[3];
  s2 = ss2[0] + ss2[1] + ss2[2] + ss2[3];
  float mu  = s * (1.0f / DIM);
  float var = s2 * (1.0f / DIM) - mu * mu;
  float rs  = rsqrtf(var + 1e-5f);
  float4 wv4 = ((const float4*)w)[t];
  float4 bv4 = ((const float4*)b)[t];
  u16 o0 = f2bf((v.x - mu) * rs * wv4.x + bv4.x);
  u16 o1 = f2bf((v.y - mu) * rs * wv4.y + bv4.y);
  u16 o2 = f2bf((v.z - mu) * rs * wv4.z + bv4.z);
  u16 o3 = f2bf((v.w - mu) * rs * wv4.w + bv4.w);
  ushort4 o; o.x = o0; o.y = o1; o.z = o2; o.w = o3;
  ((ushort4*)(h + (size_t)row * DIM))[t] = o;
}

// ---------------- Kernel 2: weight transpose -> bf16 (B^T layout) ----------------
__global__ __launch_bounds__(256) void wt_kernel(const float* __restrict__ wq,
                                                 const float* __restrict__ wk,
                                                 const float* __restrict__ wv,
                                                 u16* __restrict__ wt) {
  int mat = blockIdx.z;
  const float* w = (mat == 0) ? wq : ((mat == 1) ? wk : wv);
  __shared__ float tile[32][33];
  int j0 = blockIdx.x * 32, d0 = blockIdx.y * 32;
  int tc = threadIdx.x & 31, tr = threadIdx.x >> 5;  // 8 rows per pass
  for (int i = 0; i < 32; i += 8)
    tile[tr + i][tc] = w[(size_t)(d0 + tr + i) * DIM + j0 + tc];
  __syncthreads();
  u16* dst = wt + (size_t)mat * DIM * DIM;
  for (int i = 0; i < 32; i += 8)
    dst[(size_t)(j0 + tr + i) * DIM + d0 + tc] = f2bf(tile[tc][tr + i]);
}

// ---------------- Kernel 3: fused QKV GEMM (M=8192, N=3072, K=1024) ----------------
// m97 structure: 128x128 tile, BK=32, global_load_lds(16B), 16x16x32 bf16 MFMA.
// Epilogue: +bias, q *= QSCALE, scatter to [b][head][n][64] bf16.
__global__ __launch_bounds__(256) void gemm_qkv(const u16* __restrict__ A,
                                                const u16* __restrict__ Bt,
                                                const float* __restrict__ bq,
                                                const float* __restrict__ bk,
                                                const float* __restrict__ bv,
                                                u16* __restrict__ qo,
                                                u16* __restrict__ ko,
                                                u16* __restrict__ vo) {
  __shared__ u16 lA[128 * 32];
  __shared__ u16 lB[128 * 32];
  int t = threadIdx.x;
  int bm = blockIdx.x, bn = blockIdx.y;
  const u16* Ab = A + (size_t)bm * 128 * DIM;
  const u16* Bb = Bt + (size_t)bn * 128 * DIM;
  int lane = t & 63, w = t >> 6;
  int wm = (w >> 1) * 64, wn = (w & 1) * 64;
  int fr = lane & 15;          // fragment row (m or n within 16-tile)
  int fk = (lane >> 4) * 8;    // k offset (quad*8)
  f32x4 acc[4][4];
  for (int i = 0; i < 4; ++i) for (int j = 0; j < 4; ++j) acc[i][j] = (f32x4)(0.0f);

  for (int k0 = 0; k0 < DIM; k0 += 32) {
    __syncthreads();
    for (int r = 0; r < 2; ++r) {
      int flat = (t + r * 256) * 8;          // element index in 128x32 tile
      int m = flat >> 5, kk = flat & 31;
      async_load16(Ab + (size_t)m * DIM + k0 + kk, lA + flat);
      async_load16(Bb + (size_t)m * DIM + k0 + kk, lB + flat);
    }
    __syncthreads();
    bf16x8 af[4], bfm[4];
    for (int i = 0; i < 4; ++i) af[i]  = *(const bf16x8*)(lA + (wm + i * 16 + fr) * 32 + fk);
    for (int i = 0; i < 4; ++i) bfm[i] = *(const bf16x8*)(lB + (wn + i * 16 + fr) * 32 + fk);
    for (int i = 0; i < 4; ++i)
      for (int j = 0; j < 4; ++j)
        acc[i][j] = __builtin_amdgcn_mfma_f32_16x16x32_bf16(af[i], bfm[j], acc[i][j], 0, 0, 0);
  }

  int quad = lane >> 4;
  for (int j = 0; j < 4; ++j) {
    int gn = bn * 128 + wn + j * 16 + fr;   // 0..3071
    int mat = gn >> 10, c = gn & 1023;
    const float* bias = (mat == 0) ? bq : ((mat == 1) ? bk : bv);
    u16* out = (mat == 0) ? qo : ((mat == 1) ? ko : vo);
    float bb = bias[c];
    int head = c >> 6, d = c & 63;
    for (int i = 0; i < 4; ++i) {
      for (int r = 0; r < 4; ++r) {
        int gm = bm * 128 + wm + i * 16 + quad * 4 + r;  // 0..8191
        int b = gm >> 11, n = gm & 2047;
        float val = acc[i][j][r] + bb;
        if (mat == 0) val *= QSCALE;
        out[(((size_t)(b * HEADS + head)) * SEQ + n) * DHEAD + d] = f2bf(val);
      }
    }
  }
}

// ---------------- Kernel 4: flash attention ----------------
// grid (16 q-tiles, 64 bh). Br=Bc=128, 4 waves x 32 q-rows.
// LDS: [0,32KB) = Q / K(swizzled) / P(swizzled) overlay; [32KB, +17KB) = Vt (stride 136).
__global__ __launch_bounds__(256) void flash_attn(const u16* __restrict__ Q,
                                                  const u16* __restrict__ K,
                                                  const u16* __restrict__ V,
                                                  float* __restrict__ out) {
  __shared__ u16 smem[128 * 128 + 64 * 136];
  u16* lQ  = smem;           // 128x64, linear (staged once)
  u16* lK  = smem;           // 128x64, 16B-chunk xor swizzle
  u16* lP  = smem;           // 128x128, 16B-chunk xor swizzle
  u16* lVt = smem + 128 * 128;  // [64][136] (8-elem pad)

  int t = threadIdx.x;
  int lane = t & 63, w = t >> 6;
  int wrow = w * 32;
  int fr = lane & 15, quad = lane >> 4, fk = quad * 8;
  int qtile = blockIdx.x, bh = blockIdx.y;
  int b = bh >> 4, head = bh & 15;

  const u16* Qb = Q + ((size_t)bh * SEQ + qtile * 128) * DHEAD;
  const u16* Kbase = K + (size_t)bh * SEQ * DHEAD;
  const u16* Vbase = V + (size_t)bh * SEQ * DHEAD;

  // stage Q (contiguous 8192 elems), extract A-fragments to registers
  for (int p = 0; p < 4; ++p) {
    int flat = (t + p * 256) * 8;
    async_load16(Qb + flat, lQ + flat);
  }
  __syncthreads();
  bf16x8 aq[2][2];
  for (int mi = 0; mi < 2; ++mi)
    for (int ks = 0; ks < 2; ++ks)
      aq[mi][ks] = *(const bf16x8*)(lQ + (wrow + mi * 16 + fr) * 64 + ks * 32 + fk);

  f32x4 O[2][4];
  for (int mi = 0; mi < 2; ++mi) for (int nd = 0; nd < 4; ++nd) O[mi][nd] = (f32x4)(0.0f);
  float mold[2][4], lsum[2][4];
  for (int mi = 0; mi < 2; ++mi) for (int r = 0; r < 4; ++r) { mold[mi][r] = -1e30f; lsum[mi][r] = 0.0f; }

  for (int it = 0; it < 16; ++it) {
    const u16* Kb = Kbase + (size_t)it * 128 * DHEAD;
    const u16* Vb = Vbase + (size_t)it * 128 * DHEAD;
    __syncthreads();   // prev iter's P/Vt reads done; Q-frag reads done (it==0)

    // stage K with 16B-chunk xor swizzle (conflict-free b128 B-frag reads)
    int4 kreg[4];
    for (int p = 0; p < 4; ++p) {
      int cc = t + p * 256;
      kreg[p] = *(const int4*)(Kb + cc * 8);
    }
    for (int p = 0; p < 4; ++p) {
      int cc = t + p * 256;
      int kv = cc >> 3, c = cc & 7;
      *(int4*)(lK + kv * 64 + ((c ^ (kv & 7)) << 3)) = kreg[p];
    }
    // stage V transposed: column-parallel global reads, b128 LDS writes
    for (int p = 0; p < 4; ++p) {
      int r0 = (t >> 6) * 8 + p * 32;
      int d = t & 63;
      u16x8 pk;
      for (int i = 0; i < 8; ++i) pk[i] = Vb[(r0 + i) * DHEAD + d];
      *(u16x8*)(lVt + d * 136 + r0) = pk;
    }
    __syncthreads();

    // ---- S = Q K^T (log2-domain, scale folded into q) ----
    f32x4 S[2][8];
    for (int mi = 0; mi < 2; ++mi) for (int ni = 0; ni < 8; ++ni) S[mi][ni] = (f32x4)(0.0f);
    for (int ni = 0; ni < 8; ++ni) {
      int kv = ni * 16 + fr;
      int swz = kv & 7;
      for (int ks = 0; ks < 2; ++ks) {
        int c = ks * 4 + quad;
        bf16x8 kb = *(const bf16x8*)(lK + kv * 64 + ((c ^ swz) << 3));
        S[0][ni] = __builtin_amdgcn_mfma_f32_16x16x32_bf16(aq[0][ks], kb, S[0][ni], 0, 0, 0);
        S[1][ni] = __builtin_amdgcn_mfma_f32_16x16x32_bf16(aq[1][ks], kb, S[1][ni], 0, 0, 0);
      }
    }

    // ---- online softmax (base-2) ----
    float al[2][4];
    for (int mi = 0; mi < 2; ++mi) {
      float mx[4];
      for (int r = 0; r < 4; ++r) {
        float m0 = S[mi][0][r];
        for (int ni = 1; ni < 8; ++ni) m0 = fmaxf(m0, S[mi][ni][r]);
        mx[r] = m0;
      }
      for (int msk = 1; msk < 16; msk <<= 1)
        for (int r = 0; r < 4; ++r) mx[r] = fmaxf(mx[r], __shfl_xor(mx[r], msk));
      float rs[4];
      for (int r = 0; r < 4; ++r) {
        float mn = fmaxf(mold[mi][r], mx[r]);
        al[mi][r] = __builtin_amdgcn_exp2f(mold[mi][r] - mn);
        mold[mi][r] = mn;
        float a2 = 0.0f;
        for (int ni = 0; ni < 8; ++ni) {
          float p = __builtin_amdgcn_exp2f(S[mi][ni][r] - mn);
          S[mi][ni][r] = p;
          a2 += p;
        }
        rs[r] = a2;
      }
      for (int msk = 1; msk < 16; msk <<= 1)
        for (int r = 0; r < 4; ++r) rs[r] += __shfl_xor(rs[r], msk);
      for (int r = 0; r < 4; ++r) lsum[mi][r] = lsum[mi][r] * al[mi][r] + rs[r];
      for (int nd = 0; nd < 4; ++nd)
        for (int r = 0; r < 4; ++r) O[mi][nd][r] *= al[mi][r];
    }

    __syncthreads();   // all waves done reading lK before P overwrites it
    // ---- write P (bf16) to LDS, swizzled ----
    for (int mi = 0; mi < 2; ++mi)
      for (int ni = 0; ni < 8; ++ni) {
        int kv = ni * 16 + fr;
        int cb = kv >> 3;
        for (int r = 0; r < 4; ++r) {
          int q = wrow + mi * 16 + quad * 4 + r;
          lP[q * 128 + ((cb ^ (q & 15)) << 3) + (kv & 7)] = f2bf(S[mi][ni][r]);
        }
      }
    __syncthreads();

    // ---- O += P V ----
    for (int ks = 0; ks < 4; ++ks) {
      bf16x8 pa[2];
      for (int mi = 0; mi < 2; ++mi) {
        int q = wrow + mi * 16 + fr;
        int c = ks * 4 + quad;
        pa[mi] = *(const bf16x8*)(lP + q * 128 + ((c ^ (q & 15)) << 3));
      }
      for (int nd = 0; nd < 4; ++nd) {
        int d = nd * 16 + fr;
        bf16x8 vb = *(const bf16x8*)(lVt + d * 136 + ks * 32 + fk);
        O[0][nd] = __builtin_amdgcn_mfma_f32_16x16x32_bf16(pa[0], vb, O[0][nd], 0, 0, 0);
        O[1][nd] = __builtin_amdgcn_mfma_f32_16x16x32_bf16(pa[1], vb, O[1][nd], 0, 0, 0);
      }
    }
  }

  // ---- epilogue: O / l -> out[b][n][head*64+d] ----
  float* ob = out + ((size_t)b * SEQ + qtile * 128) * DIM + head * DHEAD;
  for (int mi = 0; mi < 2; ++mi) {
    float inv[4];
    for (int r = 0; r < 4; ++r) inv[r] = 1.0f / lsum[mi][r];
    for (int nd = 0; nd < 4; ++nd)
      for (int r = 0; r < 4; ++r) {
        int q = wrow + mi * 16 + quad * 4 + r;
        int d = nd * 16 + fr;
        ob[(size_t)q * DIM + d] = O[mi][nd][r] * inv[r];
      }
  }
}

extern "C" void kernel_launch(void* const* d_in, const int* in_sizes, int n_in,
                              void* d_out, int out_size, void* d_ws, size_t ws_size,
                              hipStream_t stream) {
  const float* x   = (const float*)d_in[0];
  const float* lnw = (const float*)d_in[1];
  const float* lnb = (const float*)d_in[2];
  const float* wq  = (const float*)d_in[3];
  const float* bq  = (const float*)d_in[4];
  const float* wk  = (const float*)d_in[5];
  const float* bk  = (const float*)d_in[6];
  const float* wv  = (const float*)d_in[7];
  const float* bv  = (const float*)d_in[8];
  float* out = (float*)d_out;

  // workspace layout (70 MB total)
  char* ws = (char*)d_ws;
  u16* h  = (u16*)(ws);                 // 8192x1024 bf16   = 16 MB
  u16* wt = (u16*)(ws + 16777216);      // 3072x1024 bf16   =  6 MB
  u16* q  = (u16*)(ws + 23068672);      // [b][h][n][64]    = 16 MB
  u16* k  = (u16*)(ws + 39845888);      // 16 MB
  u16* v  = (u16*)(ws + 56623104);      // 16 MB

  ln_kernel<<<8192, 256, 0, stream>>>(x, lnw, lnb, h);
  wt_kernel<<<dim3(32, 32, 3), 256, 0, stream>>>(wq, wk, wv, wt);
  gemm_qkv<<<dim3(64, 24), 256, 0, stream>>>(h, wt, bq, bk, bv, q, k, v);
  flash_attn<<<dim3(16, 64), 256, 0, stream>>>(q, k, v, out);
}

// Round 2
// 300.111 us; speedup vs baseline: 1.8313x; 1.8313x over previous
//
#include <hip/hip_runtime.h>
#include <hip/hip_bf16.h>
#include <stdint.h>

#define DIM    1024
#define HEADS  16
#define DHEAD  64
#define SEQ    2048
#define BATCH  4

typedef unsigned short u16;
typedef __attribute__((ext_vector_type(4))) float f32x4;
typedef __attribute__((ext_vector_type(8))) short bf16x8;

// 0.125 (1/sqrt(64)) * log2(e): scores in log2 domain -> v_exp_f32 is 2^x
#define QSCALE 0.18033688011112042f

__device__ inline u16 f2bf(float f) {
  __hip_bfloat16 h = __float2bfloat16(f);
  return *reinterpret_cast<u16*>(&h);
}

__device__ inline void async_load16(const void* g, void* l) {
  __builtin_amdgcn_global_load_lds((const __attribute__((address_space(1))) void*)g,
                                   (__attribute__((address_space(3))) void*)l, 16, 0, 0);
}

// ---------------- Kernel 1: LayerNorm -> bf16 ----------------
__global__ __launch_bounds__(256) void ln_kernel(const float* __restrict__ x,
                                                 const float* __restrict__ w,
                                                 const float* __restrict__ b,
                                                 u16* __restrict__ h) {
  int row = blockIdx.x;
  int t = threadIdx.x;
  const float4* xr = (const float4*)(x + (size_t)row * DIM);
  float4 v = xr[t];
  float s  = v.x + v.y + v.z + v.w;
  float s2 = v.x*v.x + v.y*v.y + v.z*v.z + v.w*v.w;
  for (int m = 1; m < 64; m <<= 1) { s += __shfl_xor(s, m); s2 += __shfl_xor(s2, m); }
  __shared__ float ss[4], ss2[4];
  int wid = t >> 6;
  if ((t & 63) == 0) { ss[wid] = s; ss2[wid] = s2; }
  __syncthreads();
  s  = ss[0] + ss[1] + ss[2] + ss[3];
  s2 = ss2[0] + ss2[1] + ss2[2] + ss2[3];
  float mu  = s * (1.0f / DIM);
  float var = s2 * (1.0f / DIM) - mu * mu;
  float rs  = rsqrtf(var + 1e-5f);
  float4 wv4 = ((const float4*)w)[t];
  float4 bv4 = ((const float4*)b)[t];
  ushort4 o;
  o.x = f2bf((v.x - mu) * rs * wv4.x + bv4.x);
  o.y = f2bf((v.y - mu) * rs * wv4.y + bv4.y);
  o.z = f2bf((v.z - mu) * rs * wv4.z + bv4.z);
  o.w = f2bf((v.w - mu) * rs * wv4.w + bv4.w);
  ((ushort4*)(h + (size_t)row * DIM))[t] = o;
}

// ---------------- Kernel 2: weight transpose -> bf16 (B^T layout) ----------------
__global__ __launch_bounds__(256) void wt_kernel(const float* __restrict__ wq,
                                                 const float* __restrict__ wk,
                                                 const float* __restrict__ wv,
                                                 u16* __restrict__ wt) {
  int mat = blockIdx.z;
  const float* w = (mat == 0) ? wq : ((mat == 1) ? wk : wv);
  __shared__ float tile[32][33];
  int j0 = blockIdx.x * 32, d0 = blockIdx.y * 32;
  int tc = threadIdx.x & 31, tr = threadIdx.x >> 5;
  for (int i = 0; i < 32; i += 8)
    tile[tr + i][tc] = w[(size_t)(d0 + tr + i) * DIM + j0 + tc];
  __syncthreads();
  u16* dst = wt + (size_t)mat * DIM * DIM;
  for (int i = 0; i < 32; i += 8)
    dst[(size_t)(j0 + tr + i) * DIM + d0 + tc] = f2bf(tile[tc][tr + i]);
}

// ---------------- Kernel 3: fused QKV GEMM (M=8192, N=3072, K=1024) ----------------
// Epilogue: +bias; q *= QSCALE (plain [bh][n][d]); K and V^T written in
// XOR-swizzled 128-token tile layouts so flash can global_load_lds directly.
__global__ __launch_bounds__(256) void gemm_qkv(const u16* __restrict__ A,
                                                const u16* __restrict__ Bt,
                                                const float* __restrict__ bq,
                                                const float* __restrict__ bk,
                                                const float* __restrict__ bv,
                                                u16* __restrict__ qo,
                                                u16* __restrict__ ko,
                                                u16* __restrict__ vo) {
  __shared__ u16 lA[128 * 32];
  __shared__ u16 lB[128 * 32];
  int t = threadIdx.x;
  int bm = blockIdx.x, bn = blockIdx.y;
  const u16* Ab = A + (size_t)bm * 128 * DIM;
  const u16* Bb = Bt + (size_t)bn * 128 * DIM;
  int lane = t & 63, w = t >> 6;
  int wm = (w >> 1) * 64, wn = (w & 1) * 64;
  int fr = lane & 15;
  int fk = (lane >> 4) * 8;
  f32x4 acc[4][4];
  for (int i = 0; i < 4; ++i) for (int j = 0; j < 4; ++j) acc[i][j] = (f32x4)(0.0f);

  for (int k0 = 0; k0 < DIM; k0 += 32) {
    __syncthreads();
    for (int r = 0; r < 2; ++r) {
      int flat = (t + r * 256) * 8;
      int m = flat >> 5, kk = flat & 31;
      async_load16(Ab + (size_t)m * DIM + k0 + kk, lA + flat);
      async_load16(Bb + (size_t)m * DIM + k0 + kk, lB + flat);
    }
    __syncthreads();
    bf16x8 af[4], bfm[4];
    for (int i = 0; i < 4; ++i) af[i]  = *(const bf16x8*)(lA + (wm + i * 16 + fr) * 32 + fk);
    for (int i = 0; i < 4; ++i) bfm[i] = *(const bf16x8*)(lB + (wn + i * 16 + fr) * 32 + fk);
    for (int i = 0; i < 4; ++i)
      for (int j = 0; j < 4; ++j)
        acc[i][j] = __builtin_amdgcn_mfma_f32_16x16x32_bf16(af[i], bfm[j], acc[i][j], 0, 0, 0);
  }

  int quad = lane >> 4;
  for (int j = 0; j < 4; ++j) {
    int gn = bn * 128 + wn + j * 16 + fr;   // 0..3071
    int mat = gn >> 10, c = gn & 1023;
    const float* bias = (mat == 0) ? bq : ((mat == 1) ? bk : bv);
    float bb = bias[c];
    int head = c >> 6, d = c & 63;
    for (int i = 0; i < 4; ++i) {
      for (int r = 0; r < 4; ++r) {
        int gm = bm * 128 + wm + i * 16 + quad * 4 + r;  // 0..8191
        int b = gm >> 11, n = gm & 2047;
        float val = acc[i][j][r] + bb;
        size_t bhbase = (size_t)(b * HEADS + head) * SEQ * DHEAD;
        if (mat == 0) {
          qo[bhbase + (size_t)n * DHEAD + d] = f2bf(val * QSCALE);
        } else if (mat == 1) {
          // K tile image: [kv][64] rows, 16B chunks xor-swizzled by (kv&7)
          ko[bhbase + (size_t)(n >> 7) * 8192 + (size_t)(n & 127) * 64
             + (((d >> 3) ^ (n & 7)) << 3) + (d & 7)] = f2bf(val);
        } else {
          // V^T tile image: [d][128] rows, 16B chunks xor-swizzled by (d&15)
          vo[bhbase + (size_t)(n >> 7) * 8192 + (size_t)d * 128
             + ((((n & 127) >> 3) ^ (d & 15)) << 3) + (n & 7)] = f2bf(val);
        }
      }
    }
  }
}

// ---------------- Kernel 4: flash attention ----------------
// grid (16 q-tiles, 64 bh). Br=Bc=128, 4 waves x 32 q-rows.
// S^T = K*Q^T (softmax lane-local), O^T = V^T*P^T (alpha lanes match).
// K/V^T arrive pre-swizzled -> pure global_load_lds staging, 2 barriers/iter.
// P round-trip through LDS is wave-private: no barrier.
__global__ __launch_bounds__(256, 2) void flash_attn(const u16* __restrict__ Q,
                                                     const u16* __restrict__ Ksw,
                                                     const u16* __restrict__ Vsw,
                                                     float* __restrict__ out) {
  __shared__ __align__(16) u16 smem[8192 + 8192 + 128 * 136];
  u16* lK  = smem;            // swizzled [128 kv][64 d]
  u16* lVt = smem + 8192;     // swizzled [64 d][128 n]
  u16* lP  = smem + 16384;    // [128 q][136] (16B-pad stride)
  u16* lQ  = lP;              // alias: staging only, consumed before first P write

  int t = threadIdx.x;
  int lane = t & 63, w = t >> 6;
  int wrow = w * 32;
  int fr = lane & 15, quad = lane >> 4, fk = quad * 8;
  int qtile = blockIdx.x, bh = blockIdx.y;
  int b = bh >> 4, head = bh & 15;

  const u16* Qb  = Q   + ((size_t)bh * SEQ + qtile * 128) * DHEAD;
  const u16* Kbh = Ksw + (size_t)bh * SEQ * DHEAD;
  const u16* Vbh = Vsw + (size_t)bh * SEQ * DHEAD;

  // stage Q once, pull B-fragments (n=q rows) into registers
  for (int p = 0; p < 4; ++p) {
    int flat = (t + p * 256) * 8;
    async_load16(Qb + flat, lQ + flat);
  }
  __syncthreads();
  bf16x8 aq[2][2];
  for (int mi = 0; mi < 2; ++mi)
    for (int ks = 0; ks < 2; ++ks)
      aq[mi][ks] = *(const bf16x8*)(lQ + (wrow + mi * 16 + fr) * 64 + ks * 32 + fk);

  f32x4 O[4][2];
  for (int nd = 0; nd < 4; ++nd) for (int mi = 0; mi < 2; ++mi) O[nd][mi] = (f32x4)(0.0f);
  float mold[2] = {-1e30f, -1e30f};
  float lsum[2] = {0.0f, 0.0f};

  for (int it = 0; it < 16; ++it) {
    __syncthreads();   // prev iter's lK/lVt reads (and Q-frag reads at it=0) drained
    const u16* Kb = Kbh + (size_t)it * 8192;
    const u16* Vb = Vbh + (size_t)it * 8192;
    for (int p = 0; p < 4; ++p) {
      int flat = (t + p * 256) * 8;
      async_load16(Kb + flat, lK + flat);
      async_load16(Vb + flat, lVt + flat);
    }
    __syncthreads();   // vmcnt drained: tiles ready

    // ---- T = K * Q^T : rows = k-token, cols = q ----
    f32x4 T[8][2];
    for (int ni = 0; ni < 8; ++ni) for (int mi = 0; mi < 2; ++mi) T[ni][mi] = (f32x4)(0.0f);
#pragma unroll
    for (int ni = 0; ni < 8; ++ni) {
      int kv = ni * 16 + fr;
      int sw = kv & 7;
#pragma unroll
      for (int ks = 0; ks < 2; ++ks) {
        bf16x8 kb = *(const bf16x8*)(lK + kv * 64 + (((ks * 4 + quad) ^ sw) << 3));
        T[ni][0] = __builtin_amdgcn_mfma_f32_16x16x32_bf16(kb, aq[0][ks], T[ni][0], 0, 0, 0);
        T[ni][1] = __builtin_amdgcn_mfma_f32_16x16x32_bf16(kb, aq[1][ks], T[ni][1], 0, 0, 0);
      }
    }

    // ---- online softmax (base-2), lane-local rows ----
#pragma unroll
    for (int mi = 0; mi < 2; ++mi) {
      float mx = T[0][mi][0];
#pragma unroll
      for (int ni = 0; ni < 8; ++ni)
#pragma unroll
        for (int r = 0; r < 4; ++r) mx = fmaxf(mx, T[ni][mi][r]);
      mx = fmaxf(mx, __shfl_xor(mx, 16));
      mx = fmaxf(mx, __shfl_xor(mx, 32));
      float mn = fmaxf(mold[mi], mx);
      float al = __builtin_amdgcn_exp2f(mold[mi] - mn);
      mold[mi] = mn;
      int qrow = wrow + mi * 16 + fr;
      float s = 0.0f;
#pragma unroll
      for (int ni = 0; ni < 8; ++ni) {
        float p0 = __builtin_amdgcn_exp2f(T[ni][mi][0] - mn);
        float p1 = __builtin_amdgcn_exp2f(T[ni][mi][1] - mn);
        float p2 = __builtin_amdgcn_exp2f(T[ni][mi][2] - mn);
        float p3 = __builtin_amdgcn_exp2f(T[ni][mi][3] - mn);
        s += (p0 + p1) + (p2 + p3);
        uint2 pk;
        pk.x = (uint32_t)f2bf(p0) | ((uint32_t)f2bf(p1) << 16);
        pk.y = (uint32_t)f2bf(p2) | ((uint32_t)f2bf(p3) << 16);
        *(uint2*)(lP + (size_t)qrow * 136 + ni * 16 + quad * 4) = pk;
      }
      s += __shfl_xor(s, 16);
      s += __shfl_xor(s, 32);
      lsum[mi] = lsum[mi] * al + s;
#pragma unroll
      for (int nd = 0; nd < 4; ++nd)
#pragma unroll
        for (int r = 0; r < 4; ++r) O[nd][mi][r] *= al;
    }

    // ---- O^T += V^T * P^T (wave-private P, no barrier) ----
#pragma unroll
    for (int ks = 0; ks < 4; ++ks) {
      bf16x8 pa[2];
#pragma unroll
      for (int mi = 0; mi < 2; ++mi)
        pa[mi] = *(const bf16x8*)(lP + (size_t)(wrow + mi * 16 + fr) * 136 + ks * 32 + fk);
#pragma unroll
      for (int nd = 0; nd < 4; ++nd) {
        int d = nd * 16 + fr;
        bf16x8 vb = *(const bf16x8*)(lVt + d * 128 + (((ks * 4 + quad) ^ (d & 15)) << 3));
        O[nd][0] = __builtin_amdgcn_mfma_f32_16x16x32_bf16(vb, pa[0], O[nd][0], 0, 0, 0);
        O[nd][1] = __builtin_amdgcn_mfma_f32_16x16x32_bf16(vb, pa[1], O[nd][1], 0, 0, 0);
      }
    }
  }

  // ---- epilogue: O^T/l -> out[b][n=q][head*64+d], float4 stores ----
  float* ob = out + ((size_t)b * SEQ + qtile * 128) * DIM + head * DHEAD;
#pragma unroll
  for (int mi = 0; mi < 2; ++mi) {
    float inv = 1.0f / lsum[mi];
    int q = wrow + mi * 16 + fr;
#pragma unroll
    for (int nd = 0; nd < 4; ++nd) {
      float4 vv;
      vv.x = O[nd][mi][0] * inv;
      vv.y = O[nd][mi][1] * inv;
      vv.z = O[nd][mi][2] * inv;
      vv.w = O[nd][mi][3] * inv;
      *(float4*)(ob + (size_t)q * DIM + nd * 16 + quad * 4) = vv;
    }
  }
}

extern "C" void kernel_launch(void* const* d_in, const int* in_sizes, int n_in,
                              void* d_out, int out_size, void* d_ws, size_t ws_size,
                              hipStream_t stream) {
  const float* x   = (const float*)d_in[0];
  const float* lnw = (const float*)d_in[1];
  const float* lnb = (const float*)d_in[2];
  const float* wq  = (const float*)d_in[3];
  const float* bq  = (const float*)d_in[4];
  const float* wk  = (const float*)d_in[5];
  const float* bk  = (const float*)d_in[6];
  const float* wv  = (const float*)d_in[7];
  const float* bv  = (const float*)d_in[8];
  float* out = (float*)d_out;

  char* ws = (char*)d_ws;
  u16* h  = (u16*)(ws);                 // 8192x1024 bf16   = 16 MB
  u16* wt = (u16*)(ws + 16777216);      // 3072x1024 bf16   =  6 MB
  u16* q  = (u16*)(ws + 23068672);      // [b][h][n][64]    = 16 MB
  u16* k  = (u16*)(ws + 39845888);      // swizzled tiles   = 16 MB
  u16* v  = (u16*)(ws + 56623104);      // swizzled V^T     = 16 MB

  ln_kernel<<<8192, 256, 0, stream>>>(x, lnw, lnb, h);
  wt_kernel<<<dim3(32, 32, 3), 256, 0, stream>>>(wq, wk, wv, wt);
  gemm_qkv<<<dim3(64, 24), 256, 0, stream>>>(h, wt, bq, bk, bv, q, k, v);
  flash_attn<<<dim3(16, 64), 256, 0, stream>>>(q, k, v, out);
}

// Round 3
// 272.724 us; speedup vs baseline: 2.0152x; 1.1004x over previous
//
#include <hip/hip_runtime.h>
#include <hip/hip_bf16.h>
#include <stdint.h>

#define DIM    1024
#define HEADS  16
#define DHEAD  64
#define SEQ    2048
#define BATCH  4

typedef unsigned short u16;
typedef __attribute__((ext_vector_type(4))) float f32x4;
typedef __attribute__((ext_vector_type(8))) short bf16x8;

// 0.125 (1/sqrt(64)) * log2(e): scores in log2 domain -> v_exp_f32 is 2^x
#define QSCALE 0.18033688011112042f

__device__ inline u16 f2bf(float f) {
  __hip_bfloat16 h = __float2bfloat16(f);
  return *reinterpret_cast<u16*>(&h);
}

__device__ inline uint32_t pack_bf16(float lo, float hi) {
  return (uint32_t)f2bf(lo) | ((uint32_t)f2bf(hi) << 16);
}

__device__ inline void async_load16(const void* g, void* l) {
  __builtin_amdgcn_global_load_lds((const __attribute__((address_space(1))) void*)g,
                                   (__attribute__((address_space(3))) void*)l, 16, 0, 0);
}

// ---------------- Kernel 1: LayerNorm -> bf16 ----------------
__global__ __launch_bounds__(256) void ln_kernel(const float* __restrict__ x,
                                                 const float* __restrict__ w,
                                                 const float* __restrict__ b,
                                                 u16* __restrict__ h) {
  int row = blockIdx.x;
  int t = threadIdx.x;
  const float4* xr = (const float4*)(x + (size_t)row * DIM);
  float4 v = xr[t];
  float s  = v.x + v.y + v.z + v.w;
  float s2 = v.x*v.x + v.y*v.y + v.z*v.z + v.w*v.w;
  for (int m = 1; m < 64; m <<= 1) { s += __shfl_xor(s, m); s2 += __shfl_xor(s2, m); }
  __shared__ float ss[4], ss2[4];
  int wid = t >> 6;
  if ((t & 63) == 0) { ss[wid] = s; ss2[wid] = s2; }
  __syncthreads();
  s  = ss[0] + ss[1] + ss[2] + ss[3];
  s2 = ss2[0] + ss2[1] + ss2[2] + ss2[3];
  float mu  = s * (1.0f / DIM);
  float var = s2 * (1.0f / DIM) - mu * mu;
  float rs  = rsqrtf(var + 1e-5f);
  float4 wv4 = ((const float4*)w)[t];
  float4 bv4 = ((const float4*)b)[t];
  ushort4 o;
  o.x = f2bf((v.x - mu) * rs * wv4.x + bv4.x);
  o.y = f2bf((v.y - mu) * rs * wv4.y + bv4.y);
  o.z = f2bf((v.z - mu) * rs * wv4.z + bv4.z);
  o.w = f2bf((v.w - mu) * rs * wv4.w + bv4.w);
  ((ushort4*)(h + (size_t)row * DIM))[t] = o;
}

// ---------------- Kernel 2: weight transpose -> bf16 (B^T layout) ----------------
__global__ __launch_bounds__(256) void wt_kernel(const float* __restrict__ wq,
                                                 const float* __restrict__ wk,
                                                 const float* __restrict__ wv,
                                                 u16* __restrict__ wt) {
  int mat = blockIdx.z;
  const float* w = (mat == 0) ? wq : ((mat == 1) ? wk : wv);
  __shared__ float tile[32][33];
  int j0 = blockIdx.x * 32, d0 = blockIdx.y * 32;
  int tc = threadIdx.x & 31, tr = threadIdx.x >> 5;
  for (int i = 0; i < 32; i += 8)
    tile[tr + i][tc] = w[(size_t)(d0 + tr + i) * DIM + j0 + tc];
  __syncthreads();
  u16* dst = wt + (size_t)mat * DIM * DIM;
  for (int i = 0; i < 32; i += 8)
    dst[(size_t)(j0 + tr + i) * DIM + d0 + tc] = f2bf(tile[tc][tr + i]);
}

// ---------------- Kernel 3: fused QKV GEMM (M=8192, N=3072, K=1024) ----------------
// BK=64, XOR-swizzled LDS image (swizzle folded into the GLOBAL source address
// so global_load_lds's lane-linear LDS placement yields conflict-free b128 reads).
// Epilogue: +bias; q *= QSCALE; K image swizzled; V image swizzled + kv-slot
// permuted to match flash's register-direct P fragment order.
__global__ __launch_bounds__(256) void gemm_qkv(const u16* __restrict__ A,
                                                const u16* __restrict__ Bt,
                                                const float* __restrict__ bq,
                                                const float* __restrict__ bk,
                                                const float* __restrict__ bv,
                                                u16* __restrict__ qo,
                                                u16* __restrict__ ko,
                                                u16* __restrict__ vo) {
  __shared__ u16 lA[128 * 64];
  __shared__ u16 lB[128 * 64];
  int t = threadIdx.x;
  int bm = blockIdx.x, bn = blockIdx.y;
  const u16* Ab = A + (size_t)bm * 128 * DIM;
  const u16* Bb = Bt + (size_t)bn * 128 * DIM;
  int lane = t & 63, w = t >> 6;
  int wm = (w >> 1) * 64, wn = (w & 1) * 64;
  int fr = lane & 15;
  int quad = lane >> 4;
  f32x4 acc[4][4];
  for (int i = 0; i < 4; ++i) for (int j = 0; j < 4; ++j) acc[i][j] = (f32x4)(0.0f);

  for (int k0 = 0; k0 < DIM; k0 += 64) {
    __syncthreads();
#pragma unroll
    for (int r = 0; r < 4; ++r) {
      int flat = (t + r * 256) * 8;
      int m = flat >> 6, c = (flat >> 3) & 7;
      int gk = k0 + ((c ^ (m & 7)) << 3);   // xor-swizzle via global source addr
      async_load16(Ab + (size_t)m * DIM + gk, lA + flat);
      async_load16(Bb + (size_t)m * DIM + gk, lB + flat);
    }
    __syncthreads();
#pragma unroll
    for (int ks = 0; ks < 2; ++ks) {
      bf16x8 af[4], bfm[4];
#pragma unroll
      for (int i = 0; i < 4; ++i) {
        int m = wm + i * 16 + fr;
        af[i] = *(const bf16x8*)(lA + m * 64 + (((ks * 4 + quad) ^ (fr & 7)) << 3));
      }
#pragma unroll
      for (int i = 0; i < 4; ++i) {
        int m = wn + i * 16 + fr;
        bfm[i] = *(const bf16x8*)(lB + m * 64 + (((ks * 4 + quad) ^ (fr & 7)) << 3));
      }
#pragma unroll
      for (int i = 0; i < 4; ++i)
#pragma unroll
        for (int j = 0; j < 4; ++j)
          acc[i][j] = __builtin_amdgcn_mfma_f32_16x16x32_bf16(af[i], bfm[j], acc[i][j], 0, 0, 0);
    }
  }

  for (int j = 0; j < 4; ++j) {
    int gn = bn * 128 + wn + j * 16 + fr;   // 0..3071
    int mat = gn >> 10, c = gn & 1023;
    const float* bias = (mat == 0) ? bq : ((mat == 1) ? bk : bv);
    float bb = bias[c];
    int head = c >> 6, d = c & 63;
    for (int i = 0; i < 4; ++i) {
      for (int r = 0; r < 4; ++r) {
        int gm = bm * 128 + wm + i * 16 + quad * 4 + r;  // 0..8191
        int b = gm >> 11, n = gm & 2047;
        float val = acc[i][j][r] + bb;
        size_t bhbase = (size_t)(b * HEADS + head) * SEQ * DHEAD;
        if (mat == 0) {
          qo[bhbase + (size_t)n * DHEAD + d] = f2bf(val * QSCALE);
        } else if (mat == 1) {
          // K tile image: [kv][64] rows, 16B chunks xor-swizzled by (kv&7)
          ko[bhbase + (size_t)(n >> 7) * 8192 + (size_t)(n & 127) * 64
             + (((d >> 3) ^ (n & 7)) << 3) + (d & 7)] = f2bf(val);
        } else {
          // V^T tile image: [d][128], kv-slot permuted to flash's P register
          // order (slot s: kv = 32*(s>>5) + 16*((s>>2)&1) + 4*((s>>3)&3) + (s&3)),
          // then 16B chunks xor-swizzled by (d&15).
          int n127 = n & 127;
          int kv5 = n127 & 31;
          int s = (n127 & 96) | ((kv5 & 12) << 1) | ((kv5 & 16) >> 2) | (kv5 & 3);
          vo[bhbase + (size_t)(n >> 7) * 8192 + (size_t)d * 128
             + (((s >> 3) ^ (d & 15)) << 3) + (s & 7)] = f2bf(val);
        }
      }
    }
  }
}

// ---------------- Kernel 4: flash attention ----------------
// grid (16 q-tiles, 64 bh). Br=Bc=128, 4 waves x 32 q-rows.
// S^T = K*Q^T (softmax lane-local). P^T fragments are built DIRECTLY in
// registers (packed bf16 pairs) -- the kv ordering mismatch is absorbed by
// the permuted V image -- so P never touches LDS. LDS = K + V^T = 32 KB.
__global__ __launch_bounds__(256, 3) void flash_attn(const u16* __restrict__ Q,
                                                     const u16* __restrict__ Ksw,
                                                     const u16* __restrict__ Vsw,
                                                     float* __restrict__ out) {
  __shared__ __align__(16) u16 smem[8192 + 8192];
  u16* lK  = smem;            // swizzled [128 kv][64 d]
  u16* lVt = smem + 8192;     // swizzled+permuted [64 d][128 slots]
  u16* lQ  = smem;            // alias: staging only, consumed before iter 0

  int t = threadIdx.x;
  int lane = t & 63, w = t >> 6;
  int wrow = w * 32;
  int fr = lane & 15, quad = lane >> 4, fk = quad * 8;
  int qtile = blockIdx.x, bh = blockIdx.y;
  int b = bh >> 4, head = bh & 15;

  const u16* Qb  = Q   + ((size_t)bh * SEQ + qtile * 128) * DHEAD;
  const u16* Kbh = Ksw + (size_t)bh * SEQ * DHEAD;
  const u16* Vbh = Vsw + (size_t)bh * SEQ * DHEAD;

  // stage Q once, pull B-fragments (n=q rows) into registers
  for (int p = 0; p < 4; ++p) {
    int flat = (t + p * 256) * 8;
    async_load16(Qb + flat, lQ + flat);
  }
  __syncthreads();
  bf16x8 aq[2][2];
  for (int mi = 0; mi < 2; ++mi)
    for (int ks = 0; ks < 2; ++ks)
      aq[mi][ks] = *(const bf16x8*)(lQ + (wrow + mi * 16 + fr) * 64 + ks * 32 + fk);

  f32x4 O[4][2];
  for (int nd = 0; nd < 4; ++nd) for (int mi = 0; mi < 2; ++mi) O[nd][mi] = (f32x4)(0.0f);
  float mold[2] = {-1e30f, -1e30f};
  float lsum[2] = {0.0f, 0.0f};

  for (int it = 0; it < 16; ++it) {
    __syncthreads();   // prev iter's lK/lVt reads (and Q-frag reads at it=0) drained
    const u16* Kb = Kbh + (size_t)it * 8192;
    const u16* Vb = Vbh + (size_t)it * 8192;
#pragma unroll
    for (int p = 0; p < 4; ++p) {
      int flat = (t + p * 256) * 8;
      async_load16(Kb + flat, lK + flat);
      async_load16(Vb + flat, lVt + flat);
    }
    __syncthreads();   // vmcnt drained: tiles ready

    // ---- T = K * Q^T : rows = k-token, cols = q ----
    f32x4 T[8][2];
#pragma unroll
    for (int ni = 0; ni < 8; ++ni) for (int mi = 0; mi < 2; ++mi) T[ni][mi] = (f32x4)(0.0f);
#pragma unroll
    for (int ni = 0; ni < 8; ++ni) {
      int kv = ni * 16 + fr;
      int sw = kv & 7;
#pragma unroll
      for (int ks = 0; ks < 2; ++ks) {
        bf16x8 kb = *(const bf16x8*)(lK + kv * 64 + (((ks * 4 + quad) ^ sw) << 3));
        T[ni][0] = __builtin_amdgcn_mfma_f32_16x16x32_bf16(kb, aq[0][ks], T[ni][0], 0, 0, 0);
        T[ni][1] = __builtin_amdgcn_mfma_f32_16x16x32_bf16(kb, aq[1][ks], T[ni][1], 0, 0, 0);
      }
    }

    // ---- online softmax (base-2), lane-local rows; pack P into registers ----
    uint32_t pkA[8][2], pkB[8][2];
#pragma unroll
    for (int mi = 0; mi < 2; ++mi) {
      float mx = T[0][mi][0];
#pragma unroll
      for (int ni = 0; ni < 8; ++ni)
#pragma unroll
        for (int r = 0; r < 4; ++r) mx = fmaxf(mx, T[ni][mi][r]);
      mx = fmaxf(mx, __shfl_xor(mx, 16));
      mx = fmaxf(mx, __shfl_xor(mx, 32));
      float mn = fmaxf(mold[mi], mx);
      float al = __builtin_amdgcn_exp2f(mold[mi] - mn);
      mold[mi] = mn;
      float s = 0.0f;
#pragma unroll
      for (int ni = 0; ni < 8; ++ni) {
        float p0 = __builtin_amdgcn_exp2f(T[ni][mi][0] - mn);
        float p1 = __builtin_amdgcn_exp2f(T[ni][mi][1] - mn);
        float p2 = __builtin_amdgcn_exp2f(T[ni][mi][2] - mn);
        float p3 = __builtin_amdgcn_exp2f(T[ni][mi][3] - mn);
        s += (p0 + p1) + (p2 + p3);
        pkA[ni][mi] = pack_bf16(p0, p1);
        pkB[ni][mi] = pack_bf16(p2, p3);
      }
      s += __shfl_xor(s, 16);
      s += __shfl_xor(s, 32);
      lsum[mi] = lsum[mi] * al + s;
#pragma unroll
      for (int nd = 0; nd < 4; ++nd)
#pragma unroll
        for (int r = 0; r < 4; ++r) O[nd][mi][r] *= al;
    }

    // ---- O^T += V^T * P^T ; P fragment = direct register concat ----
#pragma unroll
    for (int ks = 0; ks < 4; ++ks) {
      bf16x8 pa[2];
#pragma unroll
      for (int mi = 0; mi < 2; ++mi) {
        union { uint32_t u[4]; bf16x8 v; } cvt;
        cvt.u[0] = pkA[2 * ks][mi];
        cvt.u[1] = pkB[2 * ks][mi];
        cvt.u[2] = pkA[2 * ks + 1][mi];
        cvt.u[3] = pkB[2 * ks + 1][mi];
        pa[mi] = cvt.v;
      }
#pragma unroll
      for (int nd = 0; nd < 4; ++nd) {
        int d = nd * 16 + fr;
        bf16x8 vb = *(const bf16x8*)(lVt + d * 128 + (((ks * 4 + quad) ^ (d & 15)) << 3));
        O[nd][0] = __builtin_amdgcn_mfma_f32_16x16x32_bf16(vb, pa[0], O[nd][0], 0, 0, 0);
        O[nd][1] = __builtin_amdgcn_mfma_f32_16x16x32_bf16(vb, pa[1], O[nd][1], 0, 0, 0);
      }
    }
  }

  // ---- epilogue: O^T/l -> out[b][n=q][head*64+d], float4 stores ----
  float* ob = out + ((size_t)b * SEQ + qtile * 128) * DIM + head * DHEAD;
#pragma unroll
  for (int mi = 0; mi < 2; ++mi) {
    float inv = 1.0f / lsum[mi];
    int q = wrow + mi * 16 + fr;
#pragma unroll
    for (int nd = 0; nd < 4; ++nd) {
      float4 vv;
      vv.x = O[nd][mi][0] * inv;
      vv.y = O[nd][mi][1] * inv;
      vv.z = O[nd][mi][2] * inv;
      vv.w = O[nd][mi][3] * inv;
      *(float4*)(ob + (size_t)q * DIM + nd * 16 + quad * 4) = vv;
    }
  }
}

extern "C" void kernel_launch(void* const* d_in, const int* in_sizes, int n_in,
                              void* d_out, int out_size, void* d_ws, size_t ws_size,
                              hipStream_t stream) {
  const float* x   = (const float*)d_in[0];
  const float* lnw = (const float*)d_in[1];
  const float* lnb = (const float*)d_in[2];
  const float* wq  = (const float*)d_in[3];
  const float* bq  = (const float*)d_in[4];
  const float* wk  = (const float*)d_in[5];
  const float* bk  = (const float*)d_in[6];
  const float* wv  = (const float*)d_in[7];
  const float* bv  = (const float*)d_in[8];
  float* out = (float*)d_out;

  char* ws = (char*)d_ws;
  u16* h  = (u16*)(ws);                 // 8192x1024 bf16   = 16 MB
  u16* wt = (u16*)(ws + 16777216);      // 3072x1024 bf16   =  6 MB
  u16* q  = (u16*)(ws + 23068672);      // [b][h][n][64]    = 16 MB
  u16* k  = (u16*)(ws + 39845888);      // swizzled tiles   = 16 MB
  u16* v  = (u16*)(ws + 56623104);      // swizzled+permuted V^T = 16 MB

  ln_kernel<<<8192, 256, 0, stream>>>(x, lnw, lnb, h);
  wt_kernel<<<dim3(32, 32, 3), 256, 0, stream>>>(wq, wk, wv, wt);
  gemm_qkv<<<dim3(64, 24), 256, 0, stream>>>(h, wt, bq, bk, bv, q, k, v);
  flash_attn<<<dim3(16, 64), 256, 0, stream>>>(q, k, v, out);
}